// Round 5
// baseline (229.409 us; speedup 1.0000x reference)
//
#include <hip/hip_runtime.h>
#include <math.h>

#define T_ 128
#define B_ 512
#define S_ 128
#define D_ 128
#define V_ 50257

#define K2_VT 64
#define K2_NB ((V_ + K2_VT - 1) / K2_VT)   // 786

// ---------------- k1: M2[k][s] = sum_d transform[k][d] * tag_embed[s][d] ----------------
__global__ __launch_bounds__(128) void k1_m2(const float* __restrict__ transform,
                                             const float* __restrict__ tag_embed,
                                             float* __restrict__ M2) {
  __shared__ float te[128][129];
  int tid = threadIdx.x;
  for (int r = 0; r < 128; ++r) te[r][tid] = tag_embed[r * 128 + tid];
  __syncthreads();
  int k = blockIdx.x;
  float acc = 0.f;
  #pragma unroll 8
  for (int d = 0; d < 128; ++d) acc += transform[k * 128 + d] * te[tid][d];
  M2[k * 128 + tid] = acc;
}

// ---------------- k1b: A = softmax(tparams, axis=1) ----------------
__global__ __launch_bounds__(64) void k1b_a(const float* __restrict__ tparams,
                                            float* __restrict__ A) {
  int i = blockIdx.x;
  int l = threadIdx.x;
  float x0 = tparams[i * 128 + l];
  float x1 = tparams[i * 128 + 64 + l];
  float m = fmaxf(x0, x1);
  #pragma unroll
  for (int off = 32; off; off >>= 1) m = fmaxf(m, __shfl_xor(m, off));
  float e0 = __expf(x0 - m), e1 = __expf(x1 - m);
  float s = e0 + e1;
  #pragma unroll
  for (int off = 32; off; off >>= 1) s += __shfl_xor(s, off);
  float inv = 1.f / s;
  A[i * 128 + l]      = e0 * inv;
  A[i * 128 + 64 + l] = e1 * inv;
}

// ---------------- k2: logits = we @ M2 + corr^T, fused col-softmax partials ----------------
// 256 threads: sc = tid&31 (s = 4sc+e), vg = tid>>5 (v = v0 + 8vg + u)
// weT: transposed we-tile [d][v] in LDS; M2 staged in 2 chunks of 64 rows.
__global__ __launch_bounds__(256, 2) void k2_logits(const float* __restrict__ we,
                                                 const float* __restrict__ M2,
                                                 const float* __restrict__ corr,
                                                 float* __restrict__ logits,
                                                 float* __restrict__ pmaxb,
                                                 float* __restrict__ psumb) {
  int tid = threadIdx.x;
  int sc = tid & 31;
  int vg = tid >> 5;                // 0..7
  long v0 = (long)blockIdx.x * K2_VT;
  __shared__ float weT[128][68];    // [d][v], +4 pad (keeps 16B alignment, spreads banks)
  __shared__ float m2t[64][128];    // M2 chunk; reused as partial scratch at the end

  // stage + transpose we-tile: read we[v][d] coalesced, write weT[d][v]
  #pragma unroll
  for (int it = 0; it < 32; ++it) {
    int idx = it * 256 + tid;
    int d = idx & 127;
    int vv = idx >> 7;              // 0..63
    long v = v0 + vv;
    weT[d][vv] = (v < V_) ? we[v * 128 + d] : 0.f;
  }

  float acc[8][4];
  #pragma unroll
  for (int u = 0; u < 8; ++u)
    #pragma unroll
    for (int e = 0; e < 4; ++e) acc[u][e] = 0.f;

  #pragma unroll
  for (int c = 0; c < 2; ++c) {
    __syncthreads();                // weT staged (c=0) / prev chunk consumed (c=1)
    #pragma unroll
    for (int it = 0; it < 32; ++it) {
      int idx = it * 256 + tid;
      int kr = idx >> 7, s = idx & 127;
      m2t[kr][s] = M2[(c * 64 + kr) * 128 + s];
    }
    __syncthreads();
    #pragma unroll 8
    for (int k = 0; k < 64; ++k) {
      float4 mv = *(const float4*)&m2t[k][4 * sc];
      float4 w0 = *(const float4*)&weT[c * 64 + k][8 * vg];
      float4 w1 = *(const float4*)&weT[c * 64 + k][8 * vg + 4];
      acc[0][0] += w0.x * mv.x; acc[0][1] += w0.x * mv.y; acc[0][2] += w0.x * mv.z; acc[0][3] += w0.x * mv.w;
      acc[1][0] += w0.y * mv.x; acc[1][1] += w0.y * mv.y; acc[1][2] += w0.y * mv.z; acc[1][3] += w0.y * mv.w;
      acc[2][0] += w0.z * mv.x; acc[2][1] += w0.z * mv.y; acc[2][2] += w0.z * mv.z; acc[2][3] += w0.z * mv.w;
      acc[3][0] += w0.w * mv.x; acc[3][1] += w0.w * mv.y; acc[3][2] += w0.w * mv.z; acc[3][3] += w0.w * mv.w;
      acc[4][0] += w1.x * mv.x; acc[4][1] += w1.x * mv.y; acc[4][2] += w1.x * mv.z; acc[4][3] += w1.x * mv.w;
      acc[5][0] += w1.y * mv.x; acc[5][1] += w1.y * mv.y; acc[5][2] += w1.y * mv.z; acc[5][3] += w1.y * mv.w;
      acc[6][0] += w1.z * mv.x; acc[6][1] += w1.z * mv.y; acc[6][2] += w1.z * mv.z; acc[6][3] += w1.z * mv.w;
      acc[7][0] += w1.w * mv.x; acc[7][1] += w1.w * mv.y; acc[7][2] += w1.w * mv.z; acc[7][3] += w1.w * mv.w;
    }
  }

  // epilogue: + corr, online column partials over this thread's 8 v, float4 stores
  float lm[4], ls[4], Lst[8][4];
  #pragma unroll
  for (int e = 0; e < 4; ++e) { lm[e] = -INFINITY; ls[e] = 0.f; }
  long vbase = v0 + 8 * vg;
  #pragma unroll
  for (int e = 0; e < 4; ++e) {
    long rbase = (long)(4 * sc + e) * V_ + vbase;
    #pragma unroll
    for (int u = 0; u < 8; ++u) {
      if (vbase + u < V_) {
        float L = acc[u][e] + corr[rbase + u];
        Lst[u][e] = L;
        float nm = fmaxf(lm[e], L);
        ls[e] = ls[e] * __expf(lm[e] - nm) + __expf(L - nm);
        lm[e] = nm;
      }
    }
  }
  #pragma unroll
  for (int u = 0; u < 8; ++u) {
    long v = vbase + u;
    if (v < V_) {
      float4 st = make_float4(Lst[u][0], Lst[u][1], Lst[u][2], Lst[u][3]);
      *(float4*)&logits[v * 128 + 4 * sc] = st;
    }
  }

  __syncthreads();                  // m2t reads done -> reuse as scratch
  float* pmx = (float*)m2t;         // [8][128]
  float* psm = pmx + 8 * 128;
  #pragma unroll
  for (int e = 0; e < 4; ++e) {
    pmx[vg * 128 + 4 * sc + e] = lm[e];
    psm[vg * 128 + 4 * sc + e] = ls[e];
  }
  __syncthreads();
  if (tid < 128) {
    int s = tid;
    float m = -INFINITY, sum = 0.f;
    #pragma unroll
    for (int g = 0; g < 8; ++g) {
      float pm = pmx[g * 128 + s];
      if (pm > -1e30f) {
        float ps = psm[g * 128 + s];
        float nm = fmaxf(m, pm);
        sum = sum * __expf(m - nm) + ps * __expf(pm - nm);
        m = nm;
      }
    }
    pmaxb[blockIdx.x * 128 + s] = m;
    psumb[blockIdx.x * 128 + s] = sum;
  }
}

// ---------------- k3: reduce per-block partials -> C[s] ----------------
__global__ __launch_bounds__(256) void k3_c(const float* __restrict__ pmaxb,
                                            const float* __restrict__ psumb,
                                            float* __restrict__ C) {
  int s = blockIdx.x;
  int t = threadIdx.x;
  float m = -INFINITY, sum = 0.f;
  #pragma unroll
  for (int q = 0; q < 4; ++q) {
    int b = t + q * 256;
    if (b < K2_NB) {
      float pm = pmaxb[b * 128 + s];
      if (pm > -1e30f) {
        float ps = psumb[b * 128 + s];
        float nm = fmaxf(m, pm);
        sum = sum * __expf(m - nm) + ps * __expf(pm - nm);
        m = nm;
      }
    }
  }
  #pragma unroll
  for (int off = 32; off; off >>= 1) {
    float om = __shfl_xor(m, off);
    float os = __shfl_xor(sum, off);
    float nm = fmaxf(m, om);
    sum = sum * __expf(m - nm) + os * __expf(om - nm);
    m = nm;
  }
  __shared__ float wm[4], wsv[4];
  int lane = t & 63, wv = t >> 6;
  if (lane == 0) { wm[wv] = m; wsv[wv] = sum; }
  __syncthreads();
  if (t == 0) {
    float M = fmaxf(fmaxf(wm[0], wm[1]), fmaxf(wm[2], wm[3]));
    float S = wsv[0] * __expf(wm[0] - M) + wsv[1] * __expf(wm[1] - M)
            + wsv[2] * __expf(wm[2] - M) + wsv[3] * __expf(wm[3] - M);
    C[s] = M + __logf(S);
  }
}

// ---------------- k4: per-batch forward recurrence, 2 waves/batch, 1 barrier/iter ----
// Same structure as round 4 (proven absmax 0.0) with TWO changes:
// (1) amdgpu_waves_per_eu(1,1): round 4's allocator targeted 3 waves/SIMD and
//     squeezed the kernel to 140 VGPR (needs ~160+: Ac[128] + 8 in-flight float4
//     els reads + acc). Result: the 32 broadcast ds_read_b128 couldn't pipeline
//     (read->wait->consume, ~90cy exposed each = ~2800 cy/iter measured). With
//     the occupancy incentive removed the allocator can use the full 256 arch
//     VGPRs (+fast AGPR spill), letting els reads hoist and pipeline.
// (2) Ac[128] is loaded AFTER the em-staging burst so its live range doesn't
//     span the 127-gather staging loop (removes spill motivation).
#define K4CHAIN8(XA, XB, BASE) \
  (XA.x * Ac[(BASE)]   + XA.y * Ac[(BASE)+1] + XA.z * Ac[(BASE)+2] + XA.w * Ac[(BASE)+3] + \
   XB.x * Ac[(BASE)+4] + XB.y * Ac[(BASE)+5] + XB.z * Ac[(BASE)+6] + XB.w * Ac[(BASE)+7])

__global__ __attribute__((amdgpu_flat_work_group_size(128, 128), amdgpu_waves_per_eu(1, 1)))
void k4_rec(const int* __restrict__ words,
            const float* __restrict__ masks,
            const float* __restrict__ A,
            const float* __restrict__ C,
            const float* __restrict__ logits,
            float* __restrict__ bv) {
  const float kB = 70.70101247f;     // 102*ln2, pairs with 0x1p102f
  int j = threadIdx.x;               // 0..127: state owned by this thread
  int b = blockIdx.x;
  int lane = j & 63, w = j >> 6;     // wave 0: j 0..63, wave 1: j 64..127
  __shared__ __align__(16) float els[2][128];   // double-buffered alpha
  __shared__ float wmax[2][2];                  // double-buffered per-wave max
  __shared__ float sred[2];
  __shared__ int   wbuf[128];
  __shared__ float mbuf[128];
  __shared__ float em[127 * 128];               // 63.5 KB emission cache

  wbuf[j] = words[j * B_ + b];
  mbuf[j] = masks[j * B_ + b];
  float Cj = C[j];
  __syncthreads();                    // wbuf/mbuf ready

  // bulk emission staging: row gathers coalesced across the 128 threads.
  // em[tt][j] is written and later read by the SAME thread j (no cross-thread use).
  #pragma unroll 4
  for (int tt = 0; tt < 127; ++tt) {
    float L = logits[(unsigned)(wbuf[tt + 1] * 128 + j)];
    em[tt * 128 + j] = __expf(L - Cj + kB);
  }

  // A column load AFTER the staging burst: short preamble->loop live range.
  float Ac[128];                      // column j of A: Ac[i] = A[i][j]
  #pragma unroll
  for (int i = 0; i < 128; ++i) Ac[i] = A[i * 128 + j];

  // ---- t = 0 ----
  float a0i = -4.852030263919617f + logits[(unsigned)(wbuf[0] * 128 + j)] - Cj;
  float wm = a0i;
  #pragma unroll
  for (int off = 32; off; off >>= 1) wm = fmaxf(wm, __shfl_xor(wm, off));
  if (lane == 0) sred[w] = wm;
  __syncthreads();
  float M0 = fmaxf(sred[0], sred[1]);
  float a = __expf(a0i - M0);
  float S = M0;
  els[0][j] = a;
  float wx = a;
  #pragma unroll
  for (int off = 32; off; off >>= 1) wx = fmaxf(wx, __shfl_xor(wx, off));
  if (lane == 0) wmax[0][w] = wx;
  __syncthreads();                    // els[0], wmax[0], em staged

  for (int t = 1; t < T_; ++t) {
    const float4* E4 = (const float4*)els[(t + 1) & 1];  // buffer holding a(t-1)
    // dot: P = sum_i els[i] * A[i][j], association identical to rounds 0-2
    float G0, G1, G2, G3;
    {
      float4 x0 = E4[0], x1 = E4[1], x2 = E4[2], x3 = E4[3];
      float4 x4 = E4[4], x5 = E4[5], x6 = E4[6], x7 = E4[7];
      float p0 = K4CHAIN8(x0, x1, 0);
      float p1 = K4CHAIN8(x2, x3, 8);
      float p2 = K4CHAIN8(x4, x5, 16);
      float p3 = K4CHAIN8(x6, x7, 24);
      G0 = (p0 + p1) + (p2 + p3);
    }
    {
      float4 x0 = E4[8], x1 = E4[9], x2 = E4[10], x3 = E4[11];
      float4 x4 = E4[12], x5 = E4[13], x6 = E4[14], x7 = E4[15];
      float p0 = K4CHAIN8(x0, x1, 32);
      float p1 = K4CHAIN8(x2, x3, 40);
      float p2 = K4CHAIN8(x4, x5, 48);
      float p3 = K4CHAIN8(x6, x7, 56);
      G1 = (p0 + p1) + (p2 + p3);
    }
    {
      float4 x0 = E4[16], x1 = E4[17], x2 = E4[18], x3 = E4[19];
      float4 x4 = E4[20], x5 = E4[21], x6 = E4[22], x7 = E4[23];
      float p0 = K4CHAIN8(x0, x1, 64);
      float p1 = K4CHAIN8(x2, x3, 72);
      float p2 = K4CHAIN8(x4, x5, 80);
      float p3 = K4CHAIN8(x6, x7, 88);
      G2 = (p0 + p1) + (p2 + p3);
    }
    {
      float4 x0 = E4[24], x1 = E4[25], x2 = E4[26], x3 = E4[27];
      float4 x4 = E4[28], x5 = E4[29], x6 = E4[30], x7 = E4[31];
      float p0 = K4CHAIN8(x0, x1, 96);
      float p1 = K4CHAIN8(x2, x3, 104);
      float p2 = K4CHAIN8(x4, x5, 112);
      float p3 = K4CHAIN8(x6, x7, 120);
      G3 = (p0 + p1) + (p2 + p3);
    }
    float P = (G0 + G1) + (G2 + G3);

    float Mst = fmaxf(wmax[(t + 1) & 1][0], wmax[(t + 1) & 1][1]);
    float invM = 1.f / Mst;
    float emv = em[(t - 1) * 128 + j];
    float mm = mbuf[t];
    float nv   = (P * invM) * emv;
    float oldq = (a * invM) * 0x1p102f;
    a = mm * nv + (1.f - mm) * oldq;
    els[t & 1][j] = a;
    S += __logf(Mst) - kB;
    float wxx = a;
    #pragma unroll
    for (int off = 32; off; off >>= 1) wxx = fmaxf(wxx, __shfl_xor(wxx, off));
    if (lane == 0) wmax[t & 1][w] = wxx;
    __syncthreads();                  // single barrier: els+wmax parity covers WAR
  }

  float ss = a;
  #pragma unroll
  for (int off = 32; off; off >>= 1) ss += __shfl_xor(ss, off);
  if (lane == 0) sred[w] = ss;
  __syncthreads();
  if (j == 0) bv[b] = S + __logf(sred[0] + sred[1]);
}

// ---------------- k5: out = -sum_b bv[b] ----------------
__global__ __launch_bounds__(256) void k5_sum(const float* __restrict__ bv,
                                              float* __restrict__ out) {
  int t = threadIdx.x;
  float s = bv[t] + bv[t + 256];
  #pragma unroll
  for (int off = 32; off; off >>= 1) s += __shfl_xor(s, off);
  __shared__ float wsm[4];
  if ((t & 63) == 0) wsm[t >> 6] = s;
  __syncthreads();
  if (t == 0) out[0] = -(wsm[0] + wsm[1] + wsm[2] + wsm[3]);
}

extern "C" void kernel_launch(void* const* d_in, const int* in_sizes, int n_in,
                              void* d_out, int out_size, void* d_ws, size_t ws_size,
                              hipStream_t stream) {
  const int*   words      = (const int*)d_in[0];
  const float* masks      = (const float*)d_in[1];
  const float* tparams    = (const float*)d_in[2];
  const float* tag_embed  = (const float*)d_in[3];
  const float* word_embed = (const float*)d_in[4];
  const float* transform  = (const float*)d_in[5];
  const float* correction = (const float*)d_in[6];

  float* ws     = (float*)d_ws;
  float* M2     = ws;                 // 16384
  float* A      = ws + 16384;         // 16384
  float* C      = ws + 32768;         // 128
  float* bv     = ws + 32896;         // 512
  float* pmaxb  = ws + 33408;         // 786*128 = 100608
  float* psumb  = ws + 134016;        // 100608
  float* logits = ws + 234624;        // 6432896  (total ~26.7 MB)

  hipLaunchKernelGGL(k1_m2,    dim3(128),    dim3(128), 0, stream, transform, tag_embed, M2);
  hipLaunchKernelGGL(k1b_a,    dim3(128),    dim3(64),  0, stream, tparams, A);
  hipLaunchKernelGGL(k2_logits,dim3(K2_NB),  dim3(256), 0, stream, word_embed, M2, correction, logits, pmaxb, psumb);
  hipLaunchKernelGGL(k3_c,     dim3(S_),     dim3(256), 0, stream, pmaxb, psumb, C);
  hipLaunchKernelGGL(k4_rec,   dim3(512),    dim3(128), 0, stream, words, masks, A, C, logits, bv);
  hipLaunchKernelGGL(k5_sum,   dim3(1),      dim3(256), 0, stream, bv, (float*)d_out);
}

// Round 6
// 194.616 us; speedup vs baseline: 1.1788x; 1.1788x over previous
//
#include <hip/hip_runtime.h>
#include <math.h>

#define T_ 128
#define B_ 512
#define S_ 128
#define D_ 128
#define V_ 50257

#define K2_VT 64
#define K2_NB ((V_ + K2_VT - 1) / K2_VT)   // 786

// ---------------- k1: M2[k][s] = sum_d transform[k][d] * tag_embed[s][d] ----------------
__global__ __launch_bounds__(128) void k1_m2(const float* __restrict__ transform,
                                             const float* __restrict__ tag_embed,
                                             float* __restrict__ M2) {
  __shared__ float te[128][129];
  int tid = threadIdx.x;
  for (int r = 0; r < 128; ++r) te[r][tid] = tag_embed[r * 128 + tid];
  __syncthreads();
  int k = blockIdx.x;
  float acc = 0.f;
  #pragma unroll 8
  for (int d = 0; d < 128; ++d) acc += transform[k * 128 + d] * te[tid][d];
  M2[k * 128 + tid] = acc;
}

// ---------------- k1b: A = softmax(tparams, axis=1) ----------------
__global__ __launch_bounds__(64) void k1b_a(const float* __restrict__ tparams,
                                            float* __restrict__ A) {
  int i = blockIdx.x;
  int l = threadIdx.x;
  float x0 = tparams[i * 128 + l];
  float x1 = tparams[i * 128 + 64 + l];
  float m = fmaxf(x0, x1);
  #pragma unroll
  for (int off = 32; off; off >>= 1) m = fmaxf(m, __shfl_xor(m, off));
  float e0 = __expf(x0 - m), e1 = __expf(x1 - m);
  float s = e0 + e1;
  #pragma unroll
  for (int off = 32; off; off >>= 1) s += __shfl_xor(s, off);
  float inv = 1.f / s;
  A[i * 128 + l]      = e0 * inv;
  A[i * 128 + 64 + l] = e1 * inv;
}

// ---------------- k2: logits = we @ M2 + corr^T, fused col-softmax partials ----------------
// 256 threads: sc = tid&31 (s = 4sc+e), vg = tid>>5 (v = v0 + 8vg + u)
// weT: transposed we-tile [d][v] in LDS; M2 staged in 2 chunks of 64 rows.
__global__ __launch_bounds__(256, 2) void k2_logits(const float* __restrict__ we,
                                                 const float* __restrict__ M2,
                                                 const float* __restrict__ corr,
                                                 float* __restrict__ logits,
                                                 float* __restrict__ pmaxb,
                                                 float* __restrict__ psumb) {
  int tid = threadIdx.x;
  int sc = tid & 31;
  int vg = tid >> 5;                // 0..7
  long v0 = (long)blockIdx.x * K2_VT;
  __shared__ float weT[128][68];    // [d][v], +4 pad (keeps 16B alignment, spreads banks)
  __shared__ float m2t[64][128];    // M2 chunk; reused as partial scratch at the end

  // stage + transpose we-tile: read we[v][d] coalesced, write weT[d][v]
  #pragma unroll
  for (int it = 0; it < 32; ++it) {
    int idx = it * 256 + tid;
    int d = idx & 127;
    int vv = idx >> 7;              // 0..63
    long v = v0 + vv;
    weT[d][vv] = (v < V_) ? we[v * 128 + d] : 0.f;
  }

  float acc[8][4];
  #pragma unroll
  for (int u = 0; u < 8; ++u)
    #pragma unroll
    for (int e = 0; e < 4; ++e) acc[u][e] = 0.f;

  #pragma unroll
  for (int c = 0; c < 2; ++c) {
    __syncthreads();                // weT staged (c=0) / prev chunk consumed (c=1)
    #pragma unroll
    for (int it = 0; it < 32; ++it) {
      int idx = it * 256 + tid;
      int kr = idx >> 7, s = idx & 127;
      m2t[kr][s] = M2[(c * 64 + kr) * 128 + s];
    }
    __syncthreads();
    #pragma unroll 8
    for (int k = 0; k < 64; ++k) {
      float4 mv = *(const float4*)&m2t[k][4 * sc];
      float4 w0 = *(const float4*)&weT[c * 64 + k][8 * vg];
      float4 w1 = *(const float4*)&weT[c * 64 + k][8 * vg + 4];
      acc[0][0] += w0.x * mv.x; acc[0][1] += w0.x * mv.y; acc[0][2] += w0.x * mv.z; acc[0][3] += w0.x * mv.w;
      acc[1][0] += w0.y * mv.x; acc[1][1] += w0.y * mv.y; acc[1][2] += w0.y * mv.z; acc[1][3] += w0.y * mv.w;
      acc[2][0] += w0.z * mv.x; acc[2][1] += w0.z * mv.y; acc[2][2] += w0.z * mv.z; acc[2][3] += w0.z * mv.w;
      acc[3][0] += w0.w * mv.x; acc[3][1] += w0.w * mv.y; acc[3][2] += w0.w * mv.z; acc[3][3] += w0.w * mv.w;
      acc[4][0] += w1.x * mv.x; acc[4][1] += w1.x * mv.y; acc[4][2] += w1.x * mv.z; acc[4][3] += w1.x * mv.w;
      acc[5][0] += w1.y * mv.x; acc[5][1] += w1.y * mv.y; acc[5][2] += w1.y * mv.z; acc[5][3] += w1.y * mv.w;
      acc[6][0] += w1.z * mv.x; acc[6][1] += w1.z * mv.y; acc[6][2] += w1.z * mv.z; acc[6][3] += w1.z * mv.w;
      acc[7][0] += w1.w * mv.x; acc[7][1] += w1.w * mv.y; acc[7][2] += w1.w * mv.z; acc[7][3] += w1.w * mv.w;
    }
  }

  // epilogue: + corr, online column partials over this thread's 8 v, float4 stores
  float lm[4], ls[4], Lst[8][4];
  #pragma unroll
  for (int e = 0; e < 4; ++e) { lm[e] = -INFINITY; ls[e] = 0.f; }
  long vbase = v0 + 8 * vg;
  #pragma unroll
  for (int e = 0; e < 4; ++e) {
    long rbase = (long)(4 * sc + e) * V_ + vbase;
    #pragma unroll
    for (int u = 0; u < 8; ++u) {
      if (vbase + u < V_) {
        float L = acc[u][e] + corr[rbase + u];
        Lst[u][e] = L;
        float nm = fmaxf(lm[e], L);
        ls[e] = ls[e] * __expf(lm[e] - nm) + __expf(L - nm);
        lm[e] = nm;
      }
    }
  }
  #pragma unroll
  for (int u = 0; u < 8; ++u) {
    long v = vbase + u;
    if (v < V_) {
      float4 st = make_float4(Lst[u][0], Lst[u][1], Lst[u][2], Lst[u][3]);
      *(float4*)&logits[v * 128 + 4 * sc] = st;
    }
  }

  __syncthreads();                  // m2t reads done -> reuse as scratch
  float* pmx = (float*)m2t;         // [8][128]
  float* psm = pmx + 8 * 128;
  #pragma unroll
  for (int e = 0; e < 4; ++e) {
    pmx[vg * 128 + 4 * sc + e] = lm[e];
    psm[vg * 128 + 4 * sc + e] = ls[e];
  }
  __syncthreads();
  if (tid < 128) {
    int s = tid;
    float m = -INFINITY, sum = 0.f;
    #pragma unroll
    for (int g = 0; g < 8; ++g) {
      float pm = pmx[g * 128 + s];
      if (pm > -1e30f) {
        float ps = psm[g * 128 + s];
        float nm = fmaxf(m, pm);
        sum = sum * __expf(m - nm) + ps * __expf(pm - nm);
        m = nm;
      }
    }
    pmaxb[blockIdx.x * 128 + s] = m;
    psumb[blockIdx.x * 128 + s] = sum;
  }
}

// ---------------- k3: reduce per-block partials -> C[s] ----------------
__global__ __launch_bounds__(256) void k3_c(const float* __restrict__ pmaxb,
                                            const float* __restrict__ psumb,
                                            float* __restrict__ C) {
  int s = blockIdx.x;
  int t = threadIdx.x;
  float m = -INFINITY, sum = 0.f;
  #pragma unroll
  for (int q = 0; q < 4; ++q) {
    int b = t + q * 256;
    if (b < K2_NB) {
      float pm = pmaxb[b * 128 + s];
      if (pm > -1e30f) {
        float ps = psumb[b * 128 + s];
        float nm = fmaxf(m, pm);
        sum = sum * __expf(m - nm) + ps * __expf(pm - nm);
        m = nm;
      }
    }
  }
  #pragma unroll
  for (int off = 32; off; off >>= 1) {
    float om = __shfl_xor(m, off);
    float os = __shfl_xor(sum, off);
    float nm = fmaxf(m, om);
    sum = sum * __expf(m - nm) + os * __expf(om - nm);
    m = nm;
  }
  __shared__ float wm[4], wsv[4];
  int lane = t & 63, wv = t >> 6;
  if (lane == 0) { wm[wv] = m; wsv[wv] = sum; }
  __syncthreads();
  if (t == 0) {
    float M = fmaxf(fmaxf(wm[0], wm[1]), fmaxf(wm[2], wm[3]));
    float S = wsv[0] * __expf(wm[0] - M) + wsv[1] * __expf(wm[1] - M)
            + wsv[2] * __expf(wm[2] - M) + wsv[3] * __expf(wm[3] - M);
    C[s] = M + __logf(S);
  }
}

// ---------------- k4: forward recurrence, TWO batches per block ----------------
// Round-1's proven 512-thread structure (Ac[32]/thread, 44 VGPR, 2 barriers/iter,
// part[h] exchange) with the per-iteration fixed overhead amortized over NB=2
// batches: phase A computes partials for both batches (64 FMA/thread), phase B
// uses 256 threads (tid<128 -> batch 0, tid 128..255 -> batch 1) so its wall time
// is unchanged. Barriers/exchange paid once per 2 batches. 256 blocks (1/CU).
// All associations copied verbatim from round-1 (bit-exact, absmax 0.0 there).
#define CHAIN8(EA, EB, AC, BASE) \
  (EA.x * AC[(BASE)]   + EA.y * AC[(BASE)+1] + EA.z * AC[(BASE)+2] + EA.w * AC[(BASE)+3] + \
   EB.x * AC[(BASE)+4] + EB.y * AC[(BASE)+5] + EB.z * AC[(BASE)+6] + EB.w * AC[(BASE)+7])

#define SLICEMAX8(E0,E1,E2,E3,E4,E5,E6,E7, OUT) { \
  float4 ma = make_float4(fmaxf(E0.x,E1.x), fmaxf(E0.y,E1.y), fmaxf(E0.z,E1.z), fmaxf(E0.w,E1.w)); \
  float4 mb = make_float4(fmaxf(E2.x,E3.x), fmaxf(E2.y,E3.y), fmaxf(E2.z,E3.z), fmaxf(E2.w,E3.w)); \
  float4 mc = make_float4(fmaxf(E4.x,E5.x), fmaxf(E4.y,E5.y), fmaxf(E4.z,E5.z), fmaxf(E4.w,E5.w)); \
  float4 md = make_float4(fmaxf(E6.x,E7.x), fmaxf(E6.y,E7.y), fmaxf(E6.z,E7.z), fmaxf(E6.w,E7.w)); \
  float4 m1 = make_float4(fmaxf(ma.x,mb.x), fmaxf(ma.y,mb.y), fmaxf(ma.z,mb.z), fmaxf(ma.w,mb.w)); \
  float4 m2 = make_float4(fmaxf(mc.x,md.x), fmaxf(mc.y,md.y), fmaxf(mc.z,md.z), fmaxf(mc.w,md.w)); \
  OUT = fmaxf(fmaxf(fmaxf(m1.x,m1.y), fmaxf(m1.z,m1.w)), \
              fmaxf(fmaxf(m2.x,m2.y), fmaxf(m2.z,m2.w))); }

__global__ __launch_bounds__(512, 2) void k4_rec(const int* __restrict__ words,
                                                 const float* __restrict__ masks,
                                                 const float* __restrict__ A,
                                                 const float* __restrict__ C,
                                                 const float* __restrict__ logits,
                                                 float* __restrict__ bv) {
  const float kB = 70.70101247f;     // 102*ln2, pairs with 0x1p102f
  int tid = threadIdx.x;
  int j = tid & 127;                 // A-role state / B-role state
  int h = tid >> 7;                  // A-role partial index 0..3
  int b0 = blockIdx.x * 2;
  int lane = tid & 63;
  __shared__ __align__(16) float els[2][128];    // [g][state]
  __shared__ float part[2][4][128];              // [g][h][state]
  __shared__ __align__(16) float pmax[2][4];     // [g][h]
  __shared__ float sred[2][2];                   // [g][half]
  __shared__ int   wbuf[2][128];
  __shared__ float mbuf[2][128];

  if (tid < 256) {                   // (g, t) preamble loads
    int gg = tid >> 7, t0 = tid & 127;
    wbuf[gg][t0] = words[t0 * B_ + b0 + gg];
    mbuf[gg][t0] = masks[t0 * B_ + b0 + gg];
  }
  float Ac[32];
  #pragma unroll
  for (int k = 0; k < 32; ++k) Ac[k] = A[(h * 32 + k) * 128 + j];
  __syncthreads();                   // wbuf/mbuf ready

  int g = (tid >> 7) & 1;            // B-role batch (valid for tid<256)
  float a = 0.f, S = 0.f, em_cur = 0.f, Lnext = 0.f, Cj = 0.f, a0i = 0.f;
  if (tid < 256) {
    Cj = C[j];
    a0i = -4.852030263919617f + logits[(unsigned)(wbuf[g][0] * 128 + j)] - Cj;
    float wm = a0i;
    #pragma unroll
    for (int off = 32; off; off >>= 1) wm = fmaxf(wm, __shfl_xor(wm, off));
    if (lane == 0) sred[g][(tid >> 6) & 1] = wm;
  }
  __syncthreads();
  if (tid < 256) {
    float M0 = fmaxf(sred[g][0], sred[g][1]);
    a = __expf(a0i - M0);
    S = M0;
    els[g][j] = a;
    float L1 = logits[(unsigned)(wbuf[g][1] * 128 + j)];
    Lnext    = logits[(unsigned)(wbuf[g][2] * 128 + j)];
    em_cur = __expf(L1 - Cj + kB);
  }
  __syncthreads();

  const float4* E0 = (const float4*)&els[0][0];
  const float4* E1 = (const float4*)&els[1][0];

  for (int t = 1; t < T_; ++t) {
    // ---- phase A: partials for BOTH batches (all 512 threads) ----
    float4 x0 = E0[h * 8 + 0], x1 = E0[h * 8 + 1], x2 = E0[h * 8 + 2], x3 = E0[h * 8 + 3];
    float4 x4 = E0[h * 8 + 4], x5 = E0[h * 8 + 5], x6 = E0[h * 8 + 6], x7 = E0[h * 8 + 7];
    float4 y0 = E1[h * 8 + 0], y1 = E1[h * 8 + 1], y2 = E1[h * 8 + 2], y3 = E1[h * 8 + 3];
    float4 y4 = E1[h * 8 + 4], y5 = E1[h * 8 + 5], y6 = E1[h * 8 + 6], y7 = E1[h * 8 + 7];
    {
      float p0 = CHAIN8(x0, x1, Ac, 0);
      float p1 = CHAIN8(x2, x3, Ac, 8);
      float p2 = CHAIN8(x4, x5, Ac, 16);
      float p3 = CHAIN8(x6, x7, Ac, 24);
      part[0][h][j] = (p0 + p1) + (p2 + p3);
    }
    {
      float p0 = CHAIN8(y0, y1, Ac, 0);
      float p1 = CHAIN8(y2, y3, Ac, 8);
      float p2 = CHAIN8(y4, y5, Ac, 16);
      float p3 = CHAIN8(y6, y7, Ac, 24);
      part[1][h][j] = (p0 + p1) + (p2 + p3);
    }
    if (j == 0) {                    // 4 lanes pay for the slice-maxes (both g)
      float mx0, mx1;
      SLICEMAX8(x0, x1, x2, x3, x4, x5, x6, x7, mx0)
      SLICEMAX8(y0, y1, y2, y3, y4, y5, y6, y7, mx1)
      pmax[0][h] = mx0;
      pmax[1][h] = mx1;
    }
    float em_next = 0.f, Lf = 0.f;
    if (tid < 256) {
      if (t + 2 < T_) Lf = logits[(unsigned)(wbuf[g][t + 2] * 128 + j)];
      em_next = __expf(Lnext - Cj + kB);
    }
    __syncthreads();
    // ---- phase B: combine + update, 256 threads (one per (g, state)) ----
    if (tid < 256) {
      float4 pm4 = *(const float4*)pmax[g];
      float Mst = fmaxf(fmaxf(pm4.x, pm4.y), fmaxf(pm4.z, pm4.w));
      float invM = 1.f / Mst;
      float P = (part[g][0][j] + part[g][1][j]) + (part[g][2][j] + part[g][3][j]);
      float nv   = (P * invM) * em_cur;
      float oldq = (a * invM) * 0x1p102f;
      float mm = mbuf[g][t];
      a = mm * nv + (1.f - mm) * oldq;
      els[g][j] = a;
      S += __logf(Mst) - kB;
      em_cur = em_next;
      Lnext = Lf;
    }
    __syncthreads();
  }

  if (tid < 256) {
    float ss = a;
    #pragma unroll
    for (int off = 32; off; off >>= 1) ss += __shfl_xor(ss, off);
    if (lane == 0) sred[g][(tid >> 6) & 1] = ss;
  }
  __syncthreads();
  if (tid == 0)   bv[b0]     = S + __logf(sred[0][0] + sred[0][1]);
  if (tid == 128) bv[b0 + 1] = S + __logf(sred[1][0] + sred[1][1]);
}

// ---------------- k5: out = -sum_b bv[b] ----------------
__global__ __launch_bounds__(256) void k5_sum(const float* __restrict__ bv,
                                              float* __restrict__ out) {
  int t = threadIdx.x;
  float s = bv[t] + bv[t + 256];
  #pragma unroll
  for (int off = 32; off; off >>= 1) s += __shfl_xor(s, off);
  __shared__ float wsm[4];
  if ((t & 63) == 0) wsm[t >> 6] = s;
  __syncthreads();
  if (t == 0) out[0] = -(wsm[0] + wsm[1] + wsm[2] + wsm[3]);
}

extern "C" void kernel_launch(void* const* d_in, const int* in_sizes, int n_in,
                              void* d_out, int out_size, void* d_ws, size_t ws_size,
                              hipStream_t stream) {
  const int*   words      = (const int*)d_in[0];
  const float* masks      = (const float*)d_in[1];
  const float* tparams    = (const float*)d_in[2];
  const float* tag_embed  = (const float*)d_in[3];
  const float* word_embed = (const float*)d_in[4];
  const float* transform  = (const float*)d_in[5];
  const float* correction = (const float*)d_in[6];

  float* ws     = (float*)d_ws;
  float* M2     = ws;                 // 16384
  float* A      = ws + 16384;         // 16384
  float* C      = ws + 32768;         // 128
  float* bv     = ws + 32896;         // 512
  float* pmaxb  = ws + 33408;         // 786*128 = 100608
  float* psumb  = ws + 134016;        // 100608
  float* logits = ws + 234624;        // 6432896  (total ~26.7 MB)

  hipLaunchKernelGGL(k1_m2,    dim3(128),    dim3(128), 0, stream, transform, tag_embed, M2);
  hipLaunchKernelGGL(k1b_a,    dim3(128),    dim3(64),  0, stream, tparams, A);
  hipLaunchKernelGGL(k2_logits,dim3(K2_NB),  dim3(256), 0, stream, word_embed, M2, correction, logits, pmaxb, psumb);
  hipLaunchKernelGGL(k3_c,     dim3(S_),     dim3(256), 0, stream, pmaxb, psumb, C);
  hipLaunchKernelGGL(k4_rec,   dim3(256),    dim3(512), 0, stream, words, masks, A, C, logits, bv);
  hipLaunchKernelGGL(k5_sum,   dim3(1),      dim3(256), 0, stream, bv, (float*)d_out);
}